// Round 3
// baseline (229.117 us; speedup 1.0000x reference)
//
#include <hip/hip_runtime.h>
#include <hip/hip_bf16.h>

// FFN: out = x + fc2(relu(fc1(LN(x)))), x:(ntok,16) fp32, ntok % 512 == 0.
// R7 (resubmit — previous round failed on infra, not kernel): residency-exact
// launch. Same all-register MFMA chain as R6 (zero LDS, zero barriers), but:
//  - NIT=4 -> BT=512, grid = ntok/512 = 2048 blocks = EXACTLY 8 blocks/CU
//    (48 VGPR, 0 LDS -> 8 blocks co-resident from t=0, no workgroup churn;
//    weight-fragment prologue amortized over 128 tokens/wave).
//  - __launch_bounds__(256,8): compiler must stay <=64 VGPR so 8 blocks/CU
//    residency is legal.
//  - out stores are nontemporal: out is write-once, never re-read; keeping it
//    out of L2/L3 leaves the 256MB L3 to hold x across dispatches.

constexpr int H   = 16;
constexpr int D   = 64;
constexpr int TPI = 32;              // tokens per wave-iteration (2 n-tiles)
constexpr int NIT = 4;               // iterations per wave
constexpr int BT  = 4 * TPI * NIT;   // 512 tokens per block

typedef __attribute__((ext_vector_type(8))) short    short8;
typedef __attribute__((ext_vector_type(4))) float    floatx4;
typedef __attribute__((ext_vector_type(4))) unsigned uintx4;

__device__ inline unsigned pk2(float a, float b) { // low = a, high = b
    __hip_bfloat162 h = __float22bfloat162_rn(make_float2(a, b));
    unsigned u; __builtin_memcpy(&u, &h, 4); return u;
}
__device__ inline floatx4 relu4(floatx4 v) {
    v.x = fmaxf(v.x, 0.f); v.y = fmaxf(v.y, 0.f);
    v.z = fmaxf(v.z, 0.f); v.w = fmaxf(v.w, 0.f);
    return v;
}

// fc1 (4 m-tiles) -> relu -> register repack -> fc2 (2 k-tiles), C-in = b2.
__device__ inline floatx4 tile_ffn(const short8* a1, const short8* a2,
                                   floatx4 c2, short8 by) {
    const floatx4 z = {0.f, 0.f, 0.f, 0.f};
    floatx4 h0 = relu4(__builtin_amdgcn_mfma_f32_16x16x32_bf16(a1[0], by, z, 0, 0, 0));
    floatx4 h1 = relu4(__builtin_amdgcn_mfma_f32_16x16x32_bf16(a1[1], by, z, 0, 0, 0));
    floatx4 h2 = relu4(__builtin_amdgcn_mfma_f32_16x16x32_bf16(a1[2], by, z, 0, 0, 0));
    floatx4 h3 = relu4(__builtin_amdgcn_mfma_f32_16x16x32_bf16(a1[3], by, z, 0, 0, 0));
    uintx4 r0 = { pk2(h0.x, h0.y), pk2(h0.z, h0.w), pk2(h1.x, h1.y), pk2(h1.z, h1.w) };
    uintx4 r1 = { pk2(h2.x, h2.y), pk2(h2.z, h2.w), pk2(h3.x, h3.y), pk2(h3.z, h3.w) };
    short8 bh0, bh1;
    __builtin_memcpy(&bh0, &r0, 16);
    __builtin_memcpy(&bh1, &r1, 16);
    floatx4 o = __builtin_amdgcn_mfma_f32_16x16x32_bf16(a2[0], bh0, c2, 0, 0, 0);
    o = __builtin_amdgcn_mfma_f32_16x16x32_bf16(a2[1], bh1, o, 0, 0, 0);
    return o;
}

__global__ __launch_bounds__(256, 8) void ffn_kernel(
    const float* __restrict__ x,
    const float* __restrict__ ln_g,
    const float* __restrict__ ln_b,
    const float* __restrict__ w1,
    const float* __restrict__ b1,
    const float* __restrict__ w2,
    const float* __restrict__ b2,
    float* __restrict__ out,
    int ntok)
{
    const int tid = threadIdx.x;
    const int w = tid >> 6, l = tid & 63;
    const int li = l & 15, q = l >> 4;
    const int hb = q >> 1;           // 0: this lane's LN covers tile-A, 1: tile-B
    const int k0 = (q & 1) * 8;      // feature base this lane covers

    // ---- per-lane weight fragments, direct from global (cache-resident) ----
    // a1[mt]: A-frag of [w1 | b1 | 0] row d=16*mt+li, k = q*8 .. q*8+7
    short8 a1[4];
    #pragma unroll
    for (int mt = 0; mt < 4; mt++) {
        const int d = 16 * mt + li;
        uintx4 u = {0u, 0u, 0u, 0u};
        if (q < 2) {
            floatx4 wa = *(const floatx4*)(w1 + d * H + k0);
            floatx4 wb = *(const floatx4*)(w1 + d * H + k0 + 4);
            u.x = pk2(wa.x, wa.y); u.y = pk2(wa.z, wa.w);
            u.z = pk2(wb.x, wb.y); u.w = pk2(wb.z, wb.w);
        } else if (q == 2) {
            u.x = pk2(b1[d], 0.f);   // k=16 slot carries b1 (B-side supplies 1.0)
        }
        __builtin_memcpy(&a1[mt], &u, 16);
    }
    // a2[kt]: w2 row li, delta-permuted cols = two contiguous float4 spans:
    //   j=0..3 -> col kt*32+4q+j ; j=4..7 -> col kt*32+16+4q+(j-4)
    short8 a2[2];
    #pragma unroll
    for (int kt = 0; kt < 2; kt++) {
        floatx4 wa = *(const floatx4*)(w2 + li * D + kt * 32 + 4 * q);
        floatx4 wb = *(const floatx4*)(w2 + li * D + kt * 32 + 16 + 4 * q);
        uintx4 u = { pk2(wa.x, wa.y), pk2(wa.z, wa.w), pk2(wb.x, wb.y), pk2(wb.z, wb.w) };
        __builtin_memcpy(&a2[kt], &u, 16);
    }
    const floatx4 c2 = *(const floatx4*)(b2 + 4 * q);
    const floatx4 ga = *(const floatx4*)(ln_g + k0);
    const floatx4 gb = *(const floatx4*)(ln_g + k0 + 4);
    const floatx4 ea = *(const floatx4*)(ln_b + k0);
    const floatx4 eb = *(const floatx4*)(ln_b + k0 + 4);

    const int tok0 = blockIdx.x * BT + w * (TPI * NIT);
    // fragment-layout x pointer: own token = base + hb*16 + li, features k0..k0+7
    const float* xfrag = x + (size_t)(tok0 + hb * 16 + li) * H + k0;

    floatx4 xa = *(const floatx4*)(xfrag);
    floatx4 xb = *(const floatx4*)(xfrag + 4);

    #pragma unroll
    for (int it = 0; it < NIT; ++it) {
        // prefetch next iteration's fragment (HBM/L3-critical path)
        floatx4 na = xa, nb = xb;
        if (it + 1 < NIT) {
            const float* nx = xfrag + (size_t)(it + 1) * TPI * H;
            na = *(const floatx4*)(nx);
            nb = *(const floatx4*)(nx + 4);
        }
        const int base = tok0 + it * TPI;
        // residual loads: same lines the fragment loads touched -> L1/L2 hits
        const size_t rA = (size_t)(base + li) * H + 4 * q;
        const floatx4 xrA = *(const floatx4*)(x + rA);
        const floatx4 xrB = *(const floatx4*)(x + rA + 16 * H);

        // ---- LN over this lane's 8 features (partner = lane^16, same token) ----
        float ps = (xa.x + xa.y) + (xa.z + xa.w) + (xb.x + xb.y) + (xb.z + xb.w);
        float pq = 0.f;
        pq = fmaf(xa.x, xa.x, pq); pq = fmaf(xa.y, xa.y, pq);
        pq = fmaf(xa.z, xa.z, pq); pq = fmaf(xa.w, xa.w, pq);
        pq = fmaf(xb.x, xb.x, pq); pq = fmaf(xb.y, xb.y, pq);
        pq = fmaf(xb.z, xb.z, pq); pq = fmaf(xb.w, xb.w, pq);
        ps += __shfl_xor(ps, 16);
        pq += __shfl_xor(pq, 16);
        const float mean = ps * (1.0f / H);
        const float var  = fmaf(-mean, mean, pq * (1.0f / H));
        const float inv  = rsqrtf(var + 1e-5f);
        const float sa = inv, sb = -mean * inv;

        const float y0 = fmaf(fmaf(xa.x, sa, sb), ga.x, ea.x);
        const float y1 = fmaf(fmaf(xa.y, sa, sb), ga.y, ea.y);
        const float y2 = fmaf(fmaf(xa.z, sa, sb), ga.z, ea.z);
        const float y3 = fmaf(fmaf(xa.w, sa, sb), ga.w, ea.w);
        const float y4 = fmaf(fmaf(xb.x, sa, sb), gb.x, eb.x);
        const float y5 = fmaf(fmaf(xb.y, sa, sb), gb.y, eb.y);
        const float y6 = fmaf(fmaf(xb.z, sa, sb), gb.z, eb.z);
        const float y7 = fmaf(fmaf(xb.w, sa, sb), gb.w, eb.w);

        const unsigned p0 = pk2(y0, y1), p1 = pk2(y2, y3),
                       p2 = pk2(y4, y5), p3 = pk2(y6, y7);
        // hand tile-B's y (held by q>=2 lanes) to q<2 lanes, and vice versa
        const unsigned s0 = __shfl_xor(p0, 32), s1 = __shfl_xor(p1, 32),
                       s2 = __shfl_xor(p2, 32), s3 = __shfl_xor(p3, 32);

        const bool lo = (q < 2);
        const unsigned cq2 = (q == 2) ? 0x3F80u : 0u;  // bf16 1.0 at k=16 (b1 fold)
        uintx4 uA = { lo ? p0 : cq2, lo ? p1 : 0u, lo ? p2 : 0u, lo ? p3 : 0u };
        uintx4 uB = { lo ? s0 : cq2, lo ? s1 : 0u, lo ? s2 : 0u, lo ? s3 : 0u };
        short8 byA, byB;
        __builtin_memcpy(&byA, &uA, 16);
        __builtin_memcpy(&byB, &uB, 16);

        // ---- tile A: 16 tokens, residual + coalesced nontemporal store ----
        floatx4 oA = tile_ffn(a1, a2, c2, byA);
        oA += xrA;
        __builtin_nontemporal_store(oA, (floatx4*)(out + rA));
        // ---- tile B ----
        floatx4 oB = tile_ffn(a1, a2, c2, byB);
        oB += xrB;
        __builtin_nontemporal_store(oB, (floatx4*)(out + rA + 16 * H));

        xa = na; xb = nb;
    }
    (void)ntok;
}

extern "C" void kernel_launch(void* const* d_in, const int* in_sizes, int n_in,
                              void* d_out, int out_size, void* d_ws, size_t ws_size,
                              hipStream_t stream) {
    const float* x   = (const float*)d_in[0];
    const float* g   = (const float*)d_in[1];
    const float* be  = (const float*)d_in[2];
    const float* w1  = (const float*)d_in[3];
    const float* b1  = (const float*)d_in[4];
    const float* w2  = (const float*)d_in[5];
    const float* b2  = (const float*)d_in[6];
    float* out = (float*)d_out;
    const int ntok = in_sizes[0] / H;      // 1048576, divisible by BT=512

    const int grid = ntok / BT;
    ffn_kernel<<<grid, 256, 0, stream>>>(x, g, be, w1, b1, w2, b2, out, ntok);
}

// Round 4
// 156.480 us; speedup vs baseline: 1.4642x; 1.4642x over previous
//
#include <hip/hip_runtime.h>
#include <hip/hip_bf16.h>

// FFN: out = x + fc2(relu(fc1(LN(x)))), x:(ntok,16) fp32, ntok % 512 == 0.
// R8: R7's residency-exact launch (BT=512, grid = ntok/512 = 2048 = exactly
// 8 blocks/CU) WITHOUT the VGPR squeeze. R7's __launch_bounds__(256,8) forced
// VGPR 48->32 and spilled to scratch (FETCH/WRITE both +177MB, 3x regression).
// A 48-VGPR kernel already fits 8 waves/SIMD (halving points are 64/128/256),
// so (256,5) — the setting that measured 48 VGPR in R6 — is enough; the
// min-waves arg is a floor, not a residency cap.
//  - zero LDS, zero barriers, all-register MFMA chain (R6 structure).
//  - nontemporal output stores: out is write-once; keep L3 for x.

constexpr int H   = 16;
constexpr int D   = 64;
constexpr int TPI = 32;              // tokens per wave-iteration (2 n-tiles)
constexpr int NIT = 4;               // iterations per wave
constexpr int BT  = 4 * TPI * NIT;   // 512 tokens per block

typedef __attribute__((ext_vector_type(8))) short    short8;
typedef __attribute__((ext_vector_type(4))) float    floatx4;
typedef __attribute__((ext_vector_type(4))) unsigned uintx4;

__device__ inline unsigned pk2(float a, float b) { // low = a, high = b
    __hip_bfloat162 h = __float22bfloat162_rn(make_float2(a, b));
    unsigned u; __builtin_memcpy(&u, &h, 4); return u;
}
__device__ inline floatx4 relu4(floatx4 v) {
    v.x = fmaxf(v.x, 0.f); v.y = fmaxf(v.y, 0.f);
    v.z = fmaxf(v.z, 0.f); v.w = fmaxf(v.w, 0.f);
    return v;
}

// fc1 (4 m-tiles) -> relu -> register repack -> fc2 (2 k-tiles), C-in = b2.
__device__ inline floatx4 tile_ffn(const short8* a1, const short8* a2,
                                   floatx4 c2, short8 by) {
    const floatx4 z = {0.f, 0.f, 0.f, 0.f};
    floatx4 h0 = relu4(__builtin_amdgcn_mfma_f32_16x16x32_bf16(a1[0], by, z, 0, 0, 0));
    floatx4 h1 = relu4(__builtin_amdgcn_mfma_f32_16x16x32_bf16(a1[1], by, z, 0, 0, 0));
    floatx4 h2 = relu4(__builtin_amdgcn_mfma_f32_16x16x32_bf16(a1[2], by, z, 0, 0, 0));
    floatx4 h3 = relu4(__builtin_amdgcn_mfma_f32_16x16x32_bf16(a1[3], by, z, 0, 0, 0));
    uintx4 r0 = { pk2(h0.x, h0.y), pk2(h0.z, h0.w), pk2(h1.x, h1.y), pk2(h1.z, h1.w) };
    uintx4 r1 = { pk2(h2.x, h2.y), pk2(h2.z, h2.w), pk2(h3.x, h3.y), pk2(h3.z, h3.w) };
    short8 bh0, bh1;
    __builtin_memcpy(&bh0, &r0, 16);
    __builtin_memcpy(&bh1, &r1, 16);
    floatx4 o = __builtin_amdgcn_mfma_f32_16x16x32_bf16(a2[0], bh0, c2, 0, 0, 0);
    o = __builtin_amdgcn_mfma_f32_16x16x32_bf16(a2[1], bh1, o, 0, 0, 0);
    return o;
}

__global__ __launch_bounds__(256, 5) void ffn_kernel(
    const float* __restrict__ x,
    const float* __restrict__ ln_g,
    const float* __restrict__ ln_b,
    const float* __restrict__ w1,
    const float* __restrict__ b1,
    const float* __restrict__ w2,
    const float* __restrict__ b2,
    float* __restrict__ out,
    int ntok)
{
    const int tid = threadIdx.x;
    const int w = tid >> 6, l = tid & 63;
    const int li = l & 15, q = l >> 4;
    const int hb = q >> 1;           // 0: this lane's LN covers tile-A, 1: tile-B
    const int k0 = (q & 1) * 8;      // feature base this lane covers

    // ---- per-lane weight fragments, direct from global (cache-resident) ----
    // a1[mt]: A-frag of [w1 | b1 | 0] row d=16*mt+li, k = q*8 .. q*8+7
    short8 a1[4];
    #pragma unroll
    for (int mt = 0; mt < 4; mt++) {
        const int d = 16 * mt + li;
        uintx4 u = {0u, 0u, 0u, 0u};
        if (q < 2) {
            floatx4 wa = *(const floatx4*)(w1 + d * H + k0);
            floatx4 wb = *(const floatx4*)(w1 + d * H + k0 + 4);
            u.x = pk2(wa.x, wa.y); u.y = pk2(wa.z, wa.w);
            u.z = pk2(wb.x, wb.y); u.w = pk2(wb.z, wb.w);
        } else if (q == 2) {
            u.x = pk2(b1[d], 0.f);   // k=16 slot carries b1 (B-side supplies 1.0)
        }
        __builtin_memcpy(&a1[mt], &u, 16);
    }
    // a2[kt]: w2 row li, delta-permuted cols = two contiguous float4 spans:
    //   j=0..3 -> col kt*32+4q+j ; j=4..7 -> col kt*32+16+4q+(j-4)
    short8 a2[2];
    #pragma unroll
    for (int kt = 0; kt < 2; kt++) {
        floatx4 wa = *(const floatx4*)(w2 + li * D + kt * 32 + 4 * q);
        floatx4 wb = *(const floatx4*)(w2 + li * D + kt * 32 + 16 + 4 * q);
        uintx4 u = { pk2(wa.x, wa.y), pk2(wa.z, wa.w), pk2(wb.x, wb.y), pk2(wb.z, wb.w) };
        __builtin_memcpy(&a2[kt], &u, 16);
    }
    const floatx4 c2 = *(const floatx4*)(b2 + 4 * q);
    const floatx4 ga = *(const floatx4*)(ln_g + k0);
    const floatx4 gb = *(const floatx4*)(ln_g + k0 + 4);
    const floatx4 ea = *(const floatx4*)(ln_b + k0);
    const floatx4 eb = *(const floatx4*)(ln_b + k0 + 4);

    const int tok0 = blockIdx.x * BT + w * (TPI * NIT);
    // fragment-layout x pointer: own token = base + hb*16 + li, features k0..k0+7
    const float* xfrag = x + (size_t)(tok0 + hb * 16 + li) * H + k0;

    floatx4 xa = *(const floatx4*)(xfrag);
    floatx4 xb = *(const floatx4*)(xfrag + 4);

    #pragma unroll
    for (int it = 0; it < NIT; ++it) {
        // prefetch next iteration's fragment (HBM/L3-critical path)
        floatx4 na = xa, nb = xb;
        if (it + 1 < NIT) {
            const float* nx = xfrag + (size_t)(it + 1) * TPI * H;
            na = *(const floatx4*)(nx);
            nb = *(const floatx4*)(nx + 4);
        }
        const int base = tok0 + it * TPI;
        // residual loads: same lines the fragment loads touched -> L1/L2 hits
        const size_t rA = (size_t)(base + li) * H + 4 * q;
        const floatx4 xrA = *(const floatx4*)(x + rA);
        const floatx4 xrB = *(const floatx4*)(x + rA + 16 * H);

        // ---- LN over this lane's 8 features (partner = lane^16, same token) ----
        float ps = (xa.x + xa.y) + (xa.z + xa.w) + (xb.x + xb.y) + (xb.z + xb.w);
        float pq = 0.f;
        pq = fmaf(xa.x, xa.x, pq); pq = fmaf(xa.y, xa.y, pq);
        pq = fmaf(xa.z, xa.z, pq); pq = fmaf(xa.w, xa.w, pq);
        pq = fmaf(xb.x, xb.x, pq); pq = fmaf(xb.y, xb.y, pq);
        pq = fmaf(xb.z, xb.z, pq); pq = fmaf(xb.w, xb.w, pq);
        ps += __shfl_xor(ps, 16);
        pq += __shfl_xor(pq, 16);
        const float mean = ps * (1.0f / H);
        const float var  = fmaf(-mean, mean, pq * (1.0f / H));
        const float inv  = rsqrtf(var + 1e-5f);
        const float sa = inv, sb = -mean * inv;

        const float y0 = fmaf(fmaf(xa.x, sa, sb), ga.x, ea.x);
        const float y1 = fmaf(fmaf(xa.y, sa, sb), ga.y, ea.y);
        const float y2 = fmaf(fmaf(xa.z, sa, sb), ga.z, ea.z);
        const float y3 = fmaf(fmaf(xa.w, sa, sb), ga.w, ea.w);
        const float y4 = fmaf(fmaf(xb.x, sa, sb), gb.x, eb.x);
        const float y5 = fmaf(fmaf(xb.y, sa, sb), gb.y, eb.y);
        const float y6 = fmaf(fmaf(xb.z, sa, sb), gb.z, eb.z);
        const float y7 = fmaf(fmaf(xb.w, sa, sb), gb.w, eb.w);

        const unsigned p0 = pk2(y0, y1), p1 = pk2(y2, y3),
                       p2 = pk2(y4, y5), p3 = pk2(y6, y7);
        // hand tile-B's y (held by q>=2 lanes) to q<2 lanes, and vice versa
        const unsigned s0 = __shfl_xor(p0, 32), s1 = __shfl_xor(p1, 32),
                       s2 = __shfl_xor(p2, 32), s3 = __shfl_xor(p3, 32);

        const bool lo = (q < 2);
        const unsigned cq2 = (q == 2) ? 0x3F80u : 0u;  // bf16 1.0 at k=16 (b1 fold)
        uintx4 uA = { lo ? p0 : cq2, lo ? p1 : 0u, lo ? p2 : 0u, lo ? p3 : 0u };
        uintx4 uB = { lo ? s0 : cq2, lo ? s1 : 0u, lo ? s2 : 0u, lo ? s3 : 0u };
        short8 byA, byB;
        __builtin_memcpy(&byA, &uA, 16);
        __builtin_memcpy(&byB, &uB, 16);

        // ---- tile A: 16 tokens, residual + coalesced nontemporal store ----
        floatx4 oA = tile_ffn(a1, a2, c2, byA);
        oA += xrA;
        __builtin_nontemporal_store(oA, (floatx4*)(out + rA));
        // ---- tile B ----
        floatx4 oB = tile_ffn(a1, a2, c2, byB);
        oB += xrB;
        __builtin_nontemporal_store(oB, (floatx4*)(out + rA + 16 * H));

        xa = na; xb = nb;
    }
    (void)ntok;
}

extern "C" void kernel_launch(void* const* d_in, const int* in_sizes, int n_in,
                              void* d_out, int out_size, void* d_ws, size_t ws_size,
                              hipStream_t stream) {
    const float* x   = (const float*)d_in[0];
    const float* g   = (const float*)d_in[1];
    const float* be  = (const float*)d_in[2];
    const float* w1  = (const float*)d_in[3];
    const float* b1  = (const float*)d_in[4];
    const float* w2  = (const float*)d_in[5];
    const float* b2  = (const float*)d_in[6];
    float* out = (float*)d_out;
    const int ntok = in_sizes[0] / H;      // 1048576, divisible by BT=512

    const int grid = ntok / BT;
    ffn_kernel<<<grid, 256, 0, stream>>>(x, g, be, w1, b1, w2, b2, out, ntok);
}

// Round 7
// 147.579 us; speedup vs baseline: 1.5525x; 1.0603x over previous
//
#include <hip/hip_runtime.h>
#include <hip/hip_bf16.h>

// FFN: out = x + fc2(relu(fc1(LN(x)))), x:(ntok,16) fp32, ntok % 256 == 0.
// R9b (third submit; semantically identical to R9, source bytes changed to
// decorrelate from repeated infra "container failed twice" errors).
// Base: R6 structure (BT=256, NIT=2, plain cached stores, 43.4us/dispatch).
// Single change vs R6: residual VMEM loads eliminated. The wave's fragment
// loads (xa/xb) already cover the full 2KB of both 16-token tiles; each
// lane's epilogue residual is reconstructed via 16 loop-invariant-index
// shuffles + selects instead of 2 VMEM loads. Removes 64MB of logical x
// re-reads per dispatch and the residual L1 thrash (12 waves x 4KB > 32KB).
// Evidence carried forward: nt-stores harmful (R8: WRITE 65->106MB);
// forcing VGPR below natural 48 spills (R7: FETCH/WRITE +177MB).

constexpr int H   = 16;
constexpr int D   = 64;
constexpr int TPI = 32;
constexpr int NIT = 2;
constexpr int BT  = 4 * TPI * NIT;   // 256 tokens per block

typedef __attribute__((ext_vector_type(8))) short    short8;
typedef __attribute__((ext_vector_type(4))) float    floatx4;
typedef __attribute__((ext_vector_type(4))) unsigned uintx4;

__device__ inline unsigned pk2(float a, float b) {
    __hip_bfloat162 h = __float22bfloat162_rn(make_float2(a, b));
    unsigned u; __builtin_memcpy(&u, &h, 4); return u;
}
__device__ inline floatx4 relu4(floatx4 v) {
    v.x = fmaxf(v.x, 0.f); v.y = fmaxf(v.y, 0.f);
    v.z = fmaxf(v.z, 0.f); v.w = fmaxf(v.w, 0.f);
    return v;
}

__device__ inline floatx4 tile_ffn(const short8* a1, const short8* a2,
                                   floatx4 c2, short8 by) {
    const floatx4 z = {0.f, 0.f, 0.f, 0.f};
    floatx4 h0 = relu4(__builtin_amdgcn_mfma_f32_16x16x32_bf16(a1[0], by, z, 0, 0, 0));
    floatx4 h1 = relu4(__builtin_amdgcn_mfma_f32_16x16x32_bf16(a1[1], by, z, 0, 0, 0));
    floatx4 h2 = relu4(__builtin_amdgcn_mfma_f32_16x16x32_bf16(a1[2], by, z, 0, 0, 0));
    floatx4 h3 = relu4(__builtin_amdgcn_mfma_f32_16x16x32_bf16(a1[3], by, z, 0, 0, 0));
    uintx4 r0 = { pk2(h0.x, h0.y), pk2(h0.z, h0.w), pk2(h1.x, h1.y), pk2(h1.z, h1.w) };
    uintx4 r1 = { pk2(h2.x, h2.y), pk2(h2.z, h2.w), pk2(h3.x, h3.y), pk2(h3.z, h3.w) };
    short8 bh0, bh1;
    __builtin_memcpy(&bh0, &r0, 16);
    __builtin_memcpy(&bh1, &r1, 16);
    floatx4 o = __builtin_amdgcn_mfma_f32_16x16x32_bf16(a2[0], bh0, c2, 0, 0, 0);
    o = __builtin_amdgcn_mfma_f32_16x16x32_bf16(a2[1], bh1, o, 0, 0, 0);
    return o;
}

__global__ __launch_bounds__(256, 5) void ffn_kernel(
    const float* __restrict__ x,
    const float* __restrict__ ln_g,
    const float* __restrict__ ln_b,
    const float* __restrict__ w1,
    const float* __restrict__ b1,
    const float* __restrict__ w2,
    const float* __restrict__ b2,
    float* __restrict__ out,
    int ntok)
{
    const int tid = threadIdx.x;
    const int w  = tid >> 6;
    const int l  = tid & 63;
    const int li = l & 15;
    const int q  = l >> 4;
    const int hb = q >> 1;
    const int k0 = (q & 1) * 8;

    // Residual cross-lane sources (loop-invariant). Receiver (li,q) needs
    // floats 4q..4q+3 of token li (tile A) / token 16+li (tile B). Holder
    // lane = li + 16*(q>>1), plus 32 for tile B; holder array = xa when
    // (q&1)==0 else xb.
    const int  srcA = li + ((q >> 1) << 4);
    const int  srcB = srcA + 32;
    const bool useB = (q & 1) != 0;

    // Weight fragments, per-lane from global (cache-resident).
    short8 a1[4];
    #pragma unroll
    for (int mt = 0; mt < 4; mt++) {
        const int d = 16 * mt + li;
        uintx4 u = {0u, 0u, 0u, 0u};
        if (q < 2) {
            floatx4 wa = *(const floatx4*)(w1 + d * H + k0);
            floatx4 wb = *(const floatx4*)(w1 + d * H + k0 + 4);
            u.x = pk2(wa.x, wa.y); u.y = pk2(wa.z, wa.w);
            u.z = pk2(wb.x, wb.y); u.w = pk2(wb.z, wb.w);
        } else if (q == 2) {
            u.x = pk2(b1[d], 0.f);   // b1 folded at k=16 (B supplies 1.0)
        }
        __builtin_memcpy(&a1[mt], &u, 16);
    }
    short8 a2[2];
    #pragma unroll
    for (int kt = 0; kt < 2; kt++) {
        floatx4 wa = *(const floatx4*)(w2 + li * D + kt * 32 + 4 * q);
        floatx4 wb = *(const floatx4*)(w2 + li * D + kt * 32 + 16 + 4 * q);
        uintx4 u = { pk2(wa.x, wa.y), pk2(wa.z, wa.w), pk2(wb.x, wb.y), pk2(wb.z, wb.w) };
        __builtin_memcpy(&a2[kt], &u, 16);
    }
    const floatx4 c2 = *(const floatx4*)(b2 + 4 * q);
    const floatx4 ga = *(const floatx4*)(ln_g + k0);
    const floatx4 gb = *(const floatx4*)(ln_g + k0 + 4);
    const floatx4 ea = *(const floatx4*)(ln_b + k0);
    const floatx4 eb = *(const floatx4*)(ln_b + k0 + 4);

    const int tok0 = blockIdx.x * BT + w * (TPI * NIT);
    const float* xfrag = x + (size_t)(tok0 + hb * 16 + li) * H + k0;

    floatx4 xa = *(const floatx4*)(xfrag);
    floatx4 xb = *(const floatx4*)(xfrag + 4);

    #pragma unroll
    for (int it = 0; it < NIT; ++it) {
        floatx4 na = xa, nb = xb;
        if (it + 1 < NIT) {
            const float* nx = xfrag + (size_t)(it + 1) * TPI * H;
            na = *(const floatx4*)(nx);
            nb = *(const floatx4*)(nx + 4);
        }
        const int base = tok0 + it * TPI;
        const int rA = (base + li) * H + 4 * q;   // ntok*H < 2^31

        // Residual reconstruction — cross-lane only, no memory traffic.
        floatx4 rAa, rAb, rBa, rBb;
        rAa.x = __shfl(xa.x, srcA); rAa.y = __shfl(xa.y, srcA);
        rAa.z = __shfl(xa.z, srcA); rAa.w = __shfl(xa.w, srcA);
        rAb.x = __shfl(xb.x, srcA); rAb.y = __shfl(xb.y, srcA);
        rAb.z = __shfl(xb.z, srcA); rAb.w = __shfl(xb.w, srcA);
        rBa.x = __shfl(xa.x, srcB); rBa.y = __shfl(xa.y, srcB);
        rBa.z = __shfl(xa.z, srcB); rBa.w = __shfl(xa.w, srcB);
        rBb.x = __shfl(xb.x, srcB); rBb.y = __shfl(xb.y, srcB);
        rBb.z = __shfl(xb.z, srcB); rBb.w = __shfl(xb.w, srcB);
        const floatx4 xrA = useB ? rAb : rAa;
        const floatx4 xrB = useB ? rBb : rBa;

        // LayerNorm (partner lane = l^16 holds the other 8 features).
        float ps = (xa.x + xa.y) + (xa.z + xa.w) + (xb.x + xb.y) + (xb.z + xb.w);
        float pq = 0.f;
        pq = fmaf(xa.x, xa.x, pq); pq = fmaf(xa.y, xa.y, pq);
        pq = fmaf(xa.z, xa.z, pq); pq = fmaf(xa.w, xa.w, pq);
        pq = fmaf(xb.x, xb.x, pq); pq = fmaf(xb.y, xb.y, pq);
        pq = fmaf(xb.z, xb.z, pq); pq = fmaf(xb.w, xb.w, pq);
        ps += __shfl_xor(ps, 16);
        pq += __shfl_xor(pq, 16);
        const float mean = ps * (1.0f / H);
        const float var  = fmaf(-mean, mean, pq * (1.0f / H));
        const float inv  = rsqrtf(var + 1e-5f);
        const float sa = inv, sb = -mean * inv;

        const float y0 = fmaf(fmaf(xa.x, sa, sb), ga.x, ea.x);
        const float y1 = fmaf(fmaf(xa.y, sa, sb), ga.y, ea.y);
        const float y2 = fmaf(fmaf(xa.z, sa, sb), ga.z, ea.z);
        const float y3 = fmaf(fmaf(xa.w, sa, sb), ga.w, ea.w);
        const float y4 = fmaf(fmaf(xb.x, sa, sb), gb.x, eb.x);
        const float y5 = fmaf(fmaf(xb.y, sa, sb), gb.y, eb.y);
        const float y6 = fmaf(fmaf(xb.z, sa, sb), gb.z, eb.z);
        const float y7 = fmaf(fmaf(xb.w, sa, sb), gb.w, eb.w);

        const unsigned p0 = pk2(y0, y1), p1 = pk2(y2, y3),
                       p2 = pk2(y4, y5), p3 = pk2(y6, y7);
        const unsigned s0 = __shfl_xor(p0, 32), s1 = __shfl_xor(p1, 32),
                       s2 = __shfl_xor(p2, 32), s3 = __shfl_xor(p3, 32);

        const bool lo = (q < 2);
        const unsigned cq2 = (q == 2) ? 0x3F80u : 0u;
        uintx4 uA = { lo ? p0 : cq2, lo ? p1 : 0u, lo ? p2 : 0u, lo ? p3 : 0u };
        uintx4 uB = { lo ? s0 : cq2, lo ? s1 : 0u, lo ? s2 : 0u, lo ? s3 : 0u };
        short8 byA, byB;
        __builtin_memcpy(&byA, &uA, 16);
        __builtin_memcpy(&byB, &uB, 16);

        floatx4 oA = tile_ffn(a1, a2, c2, byA);
        oA += xrA;
        *(floatx4*)(out + rA) = oA;

        floatx4 oB = tile_ffn(a1, a2, c2, byB);
        oB += xrB;
        *(floatx4*)(out + rA + 16 * H) = oB;

        xa = na; xb = nb;
    }
    (void)ntok;
}

extern "C" void kernel_launch(void* const* d_in, const int* in_sizes, int n_in,
                              void* d_out, int out_size, void* d_ws, size_t ws_size,
                              hipStream_t stream) {
    const float* x   = (const float*)d_in[0];
    const float* g   = (const float*)d_in[1];
    const float* be  = (const float*)d_in[2];
    const float* w1  = (const float*)d_in[3];
    const float* b1  = (const float*)d_in[4];
    const float* w2  = (const float*)d_in[5];
    const float* b2  = (const float*)d_in[6];
    float* out = (float*)d_out;
    const int ntok = in_sizes[0] / H;      // 1048576, divisible by BT=256

    const int grid = ntok / BT;
    ffn_kernel<<<grid, 256, 0, stream>>>(x, g, be, w1, b1, w2, b2, out, ntok);
}

// Round 8
// 134.053 us; speedup vs baseline: 1.7091x; 1.1009x over previous
//
#include <hip/hip_runtime.h>
#include <hip/hip_bf16.h>

// FFN: out = x + fc2(relu(fc1(LN(x)))), x:(ntok,16) fp32, ntok % 512 == 0.
// R10: deep load batching. Cross-round model: R5/R6/R8/R9b all achieve a
// constant ~2.3-2.4 TB/s regardless of structure => concurrency-capped
// (Little's law: ~12 waves/CU x ~4 outstanding 16B loads ~ 0.8KB in flight
// -> ~2 TB/s at ~375ns latency). Fix: 3-deep software pipeline — loads for
// iterations it..it+2 always in flight (12 dwordx4/wave vs R6's ~4).
//  - NIT=4, BT=512, grid=2048; residual loads KEPT (R9b: removing them cost
//    +10us — they are free concurrency, L1/L2-resident).
//  - plain cached stores (R8: nt-stores inflate WRITE 65->106MB).
//  - __launch_bounds__(256,4): 128-VGPR cap > pipeline's ~110 need; never
//    force below natural allocation (R7: forced 32 VGPR -> +177MB spill).

constexpr int H   = 16;
constexpr int D   = 64;
constexpr int TPI = 32;              // tokens per wave-iteration (2 n-tiles)
constexpr int NIT = 4;               // iterations per wave
constexpr int PF  = 2;               // load-ahead distance (depth = PF+1)
constexpr int BT  = 4 * TPI * NIT;   // 512 tokens per block

typedef __attribute__((ext_vector_type(8))) short    short8;
typedef __attribute__((ext_vector_type(4))) float    floatx4;
typedef __attribute__((ext_vector_type(4))) unsigned uintx4;

__device__ inline unsigned pk2(float a, float b) { // low = a, high = b
    __hip_bfloat162 h = __float22bfloat162_rn(make_float2(a, b));
    unsigned u; __builtin_memcpy(&u, &h, 4); return u;
}
__device__ inline floatx4 relu4(floatx4 v) {
    v.x = fmaxf(v.x, 0.f); v.y = fmaxf(v.y, 0.f);
    v.z = fmaxf(v.z, 0.f); v.w = fmaxf(v.w, 0.f);
    return v;
}

// fc1 (4 m-tiles) -> relu -> register repack -> fc2 (2 k-tiles), C-in = b2.
__device__ inline floatx4 tile_ffn(const short8* a1, const short8* a2,
                                   floatx4 c2, short8 by) {
    const floatx4 z = {0.f, 0.f, 0.f, 0.f};
    floatx4 h0 = relu4(__builtin_amdgcn_mfma_f32_16x16x32_bf16(a1[0], by, z, 0, 0, 0));
    floatx4 h1 = relu4(__builtin_amdgcn_mfma_f32_16x16x32_bf16(a1[1], by, z, 0, 0, 0));
    floatx4 h2 = relu4(__builtin_amdgcn_mfma_f32_16x16x32_bf16(a1[2], by, z, 0, 0, 0));
    floatx4 h3 = relu4(__builtin_amdgcn_mfma_f32_16x16x32_bf16(a1[3], by, z, 0, 0, 0));
    uintx4 r0 = { pk2(h0.x, h0.y), pk2(h0.z, h0.w), pk2(h1.x, h1.y), pk2(h1.z, h1.w) };
    uintx4 r1 = { pk2(h2.x, h2.y), pk2(h2.z, h2.w), pk2(h3.x, h3.y), pk2(h3.z, h3.w) };
    short8 bh0, bh1;
    __builtin_memcpy(&bh0, &r0, 16);
    __builtin_memcpy(&bh1, &r1, 16);
    floatx4 o = __builtin_amdgcn_mfma_f32_16x16x32_bf16(a2[0], bh0, c2, 0, 0, 0);
    o = __builtin_amdgcn_mfma_f32_16x16x32_bf16(a2[1], bh1, o, 0, 0, 0);
    return o;
}

// issue the 4 loads (fragment pair + residual pair) for pipeline slot j
#define LOAD_IT(j)                                                      \
    do {                                                                \
        fa[j] = *(const floatx4*)(xfr + (j) * TPI * H);                 \
        fb[j] = *(const floatx4*)(xfr + (j) * TPI * H + 4);             \
        ra[j] = *(const floatx4*)(xrs + (j) * TPI * H);                 \
        rb[j] = *(const floatx4*)(xrs + (j) * TPI * H + 16 * H);        \
    } while (0)

__global__ __launch_bounds__(256, 4) void ffn_kernel(
    const float* __restrict__ x,
    const float* __restrict__ ln_g,
    const float* __restrict__ ln_b,
    const float* __restrict__ w1,
    const float* __restrict__ b1,
    const float* __restrict__ w2,
    const float* __restrict__ b2,
    float* __restrict__ out,
    int ntok)
{
    const int tid = threadIdx.x;
    const int w = tid >> 6, l = tid & 63;
    const int li = l & 15, q = l >> 4;
    const int hb = q >> 1;           // 0: this lane's LN covers tile-A, 1: tile-B
    const int k0 = (q & 1) * 8;      // feature base this lane covers

    // ---- per-lane weight fragments, direct from global (cache-resident) ----
    short8 a1[4];
    #pragma unroll
    for (int mt = 0; mt < 4; mt++) {
        const int d = 16 * mt + li;
        uintx4 u = {0u, 0u, 0u, 0u};
        if (q < 2) {
            floatx4 wa = *(const floatx4*)(w1 + d * H + k0);
            floatx4 wb = *(const floatx4*)(w1 + d * H + k0 + 4);
            u.x = pk2(wa.x, wa.y); u.y = pk2(wa.z, wa.w);
            u.z = pk2(wb.x, wb.y); u.w = pk2(wb.z, wb.w);
        } else if (q == 2) {
            u.x = pk2(b1[d], 0.f);   // k=16 slot carries b1 (B-side supplies 1.0)
        }
        __builtin_memcpy(&a1[mt], &u, 16);
    }
    // a2[kt]: w2 row li, delta-permuted cols = two contiguous float4 spans
    short8 a2[2];
    #pragma unroll
    for (int kt = 0; kt < 2; kt++) {
        floatx4 wa = *(const floatx4*)(w2 + li * D + kt * 32 + 4 * q);
        floatx4 wb = *(const floatx4*)(w2 + li * D + kt * 32 + 16 + 4 * q);
        uintx4 u = { pk2(wa.x, wa.y), pk2(wa.z, wa.w), pk2(wb.x, wb.y), pk2(wb.z, wb.w) };
        __builtin_memcpy(&a2[kt], &u, 16);
    }
    const floatx4 c2 = *(const floatx4*)(b2 + 4 * q);
    const floatx4 ga = *(const floatx4*)(ln_g + k0);
    const floatx4 gb = *(const floatx4*)(ln_g + k0 + 4);
    const floatx4 ea = *(const floatx4*)(ln_b + k0);
    const floatx4 eb = *(const floatx4*)(ln_b + k0 + 4);

    const int tok0 = blockIdx.x * BT + w * (TPI * NIT);
    // fragment ptr: own token = tok0 + hb*16 + li, features k0..k0+7
    const float* xfr = x + (size_t)(tok0 + hb * 16 + li) * H + k0;
    // residual ptr (tile A of iter 0): token tok0 + li, floats 4q..4q+3
    const float* xrs = x + (size_t)(tok0 + li) * H + 4 * q;

    floatx4 fa[NIT], fb[NIT], ra[NIT], rb[NIT];
    // ---- prime the pipeline: iterations 0..PF-1 in flight ----
    #pragma unroll
    for (int p = 0; p < PF; p++) LOAD_IT(p);

    #pragma unroll
    for (int it = 0; it < NIT; ++it) {
        // keep depth: issue loads for it+PF before consuming it
        if (it + PF < NIT) LOAD_IT(it + PF);

        const floatx4 xa = fa[it], xb = fb[it];
        const int rA = (tok0 + it * TPI + li) * H + 4 * q;  // ntok*H < 2^31

        // ---- LN over this lane's 8 features (partner = lane^16) ----
        float ps = (xa.x + xa.y) + (xa.z + xa.w) + (xb.x + xb.y) + (xb.z + xb.w);
        float pq = 0.f;
        pq = fmaf(xa.x, xa.x, pq); pq = fmaf(xa.y, xa.y, pq);
        pq = fmaf(xa.z, xa.z, pq); pq = fmaf(xa.w, xa.w, pq);
        pq = fmaf(xb.x, xb.x, pq); pq = fmaf(xb.y, xb.y, pq);
        pq = fmaf(xb.z, xb.z, pq); pq = fmaf(xb.w, xb.w, pq);
        ps += __shfl_xor(ps, 16);
        pq += __shfl_xor(pq, 16);
        const float mean = ps * (1.0f / H);
        const float var  = fmaf(-mean, mean, pq * (1.0f / H));
        const float inv  = rsqrtf(var + 1e-5f);
        const float sa = inv, sb = -mean * inv;

        const float y0 = fmaf(fmaf(xa.x, sa, sb), ga.x, ea.x);
        const float y1 = fmaf(fmaf(xa.y, sa, sb), ga.y, ea.y);
        const float y2 = fmaf(fmaf(xa.z, sa, sb), ga.z, ea.z);
        const float y3 = fmaf(fmaf(xa.w, sa, sb), ga.w, ea.w);
        const float y4 = fmaf(fmaf(xb.x, sa, sb), gb.x, eb.x);
        const float y5 = fmaf(fmaf(xb.y, sa, sb), gb.y, eb.y);
        const float y6 = fmaf(fmaf(xb.z, sa, sb), gb.z, eb.z);
        const float y7 = fmaf(fmaf(xb.w, sa, sb), gb.w, eb.w);

        const unsigned p0 = pk2(y0, y1), p1 = pk2(y2, y3),
                       p2 = pk2(y4, y5), p3 = pk2(y6, y7);
        // hand tile-B's y (held by q>=2 lanes) to q<2 lanes, and vice versa
        const unsigned s0 = __shfl_xor(p0, 32), s1 = __shfl_xor(p1, 32),
                       s2 = __shfl_xor(p2, 32), s3 = __shfl_xor(p3, 32);

        const bool lo = (q < 2);
        const unsigned cq2 = (q == 2) ? 0x3F80u : 0u;  // bf16 1.0 at k=16 (b1 fold)
        uintx4 uA = { lo ? p0 : cq2, lo ? p1 : 0u, lo ? p2 : 0u, lo ? p3 : 0u };
        uintx4 uB = { lo ? s0 : cq2, lo ? s1 : 0u, lo ? s2 : 0u, lo ? s3 : 0u };
        short8 byA, byB;
        __builtin_memcpy(&byA, &uA, 16);
        __builtin_memcpy(&byB, &uB, 16);

        // ---- tile A: 16 tokens, residual + coalesced store ----
        floatx4 oA = tile_ffn(a1, a2, c2, byA);
        oA += ra[it];
        *(floatx4*)(out + rA) = oA;
        // ---- tile B ----
        floatx4 oB = tile_ffn(a1, a2, c2, byB);
        oB += rb[it];
        *(floatx4*)(out + rA + 16 * H) = oB;
    }
    (void)ntok;
}

extern "C" void kernel_launch(void* const* d_in, const int* in_sizes, int n_in,
                              void* d_out, int out_size, void* d_ws, size_t ws_size,
                              hipStream_t stream) {
    const float* x   = (const float*)d_in[0];
    const float* g   = (const float*)d_in[1];
    const float* be  = (const float*)d_in[2];
    const float* w1  = (const float*)d_in[3];
    const float* b1  = (const float*)d_in[4];
    const float* w2  = (const float*)d_in[5];
    const float* b2  = (const float*)d_in[6];
    float* out = (float*)d_out;
    const int ntok = in_sizes[0] / H;      // 1048576, divisible by BT=512

    const int grid = ntok / BT;
    ffn_kernel<<<grid, 256, 0, stream>>>(x, g, be, w1, b1, w2, b2, out, ntok);
}

// Round 9
// 133.439 us; speedup vs baseline: 1.7170x; 1.0046x over previous
//
#include <hip/hip_runtime.h>
#include <hip/hip_bf16.h>

// FFN: out = x + fc2(relu(fc1(LN(x)))), x:(ntok,16) fp32, ntok % 512 == 0.
// R11: R10's pipeline, actually enforced. R10 intended a 3-deep load pipeline
// but the compiler sank the loads to use (proof: VGPR=56, impossible for a
// held 3-deep pipeline; dur/BW identical to R6). Fix:
//  - prime ALL 4 iteration slots (16 x dwordx4 per wave) up front, then
//    __builtin_amdgcn_sched_barrier(0): fully-unrolled single-block kernel
//    means only the machine scheduler could sink the loads, and the barrier
//    blocks it. VGPR count is the verification signal (~120 = held, 56 = not).
//  - consumption order == issue order -> compiler emits counted vmcnt waits
//    (12/8/4/0), overlapping load returns with compute.
//  - residual loads kept (R9b: they are free concurrency), plain stores (R8),
//    launch_bounds(256,4) = 128-VGPR cap, no forced squeeze below natural
//    allocation (R7 spill lesson).

constexpr int H   = 16;
constexpr int D   = 64;
constexpr int TPI = 32;              // tokens per wave-iteration (2 n-tiles)
constexpr int NIT = 4;               // iterations per wave
constexpr int BT  = 4 * TPI * NIT;   // 512 tokens per block

typedef __attribute__((ext_vector_type(8))) short    short8;
typedef __attribute__((ext_vector_type(4))) float    floatx4;
typedef __attribute__((ext_vector_type(4))) unsigned uintx4;

__device__ inline unsigned pk2(float a, float b) { // low = a, high = b
    __hip_bfloat162 h = __float22bfloat162_rn(make_float2(a, b));
    unsigned u; __builtin_memcpy(&u, &h, 4); return u;
}
__device__ inline floatx4 relu4(floatx4 v) {
    v.x = fmaxf(v.x, 0.f); v.y = fmaxf(v.y, 0.f);
    v.z = fmaxf(v.z, 0.f); v.w = fmaxf(v.w, 0.f);
    return v;
}

// fc1 (4 m-tiles) -> relu -> register repack -> fc2 (2 k-tiles), C-in = b2.
__device__ inline floatx4 tile_ffn(const short8* a1, const short8* a2,
                                   floatx4 c2, short8 by) {
    const floatx4 z = {0.f, 0.f, 0.f, 0.f};
    floatx4 h0 = relu4(__builtin_amdgcn_mfma_f32_16x16x32_bf16(a1[0], by, z, 0, 0, 0));
    floatx4 h1 = relu4(__builtin_amdgcn_mfma_f32_16x16x32_bf16(a1[1], by, z, 0, 0, 0));
    floatx4 h2 = relu4(__builtin_amdgcn_mfma_f32_16x16x32_bf16(a1[2], by, z, 0, 0, 0));
    floatx4 h3 = relu4(__builtin_amdgcn_mfma_f32_16x16x32_bf16(a1[3], by, z, 0, 0, 0));
    uintx4 r0 = { pk2(h0.x, h0.y), pk2(h0.z, h0.w), pk2(h1.x, h1.y), pk2(h1.z, h1.w) };
    uintx4 r1 = { pk2(h2.x, h2.y), pk2(h2.z, h2.w), pk2(h3.x, h3.y), pk2(h3.z, h3.w) };
    short8 bh0, bh1;
    __builtin_memcpy(&bh0, &r0, 16);
    __builtin_memcpy(&bh1, &r1, 16);
    floatx4 o = __builtin_amdgcn_mfma_f32_16x16x32_bf16(a2[0], bh0, c2, 0, 0, 0);
    o = __builtin_amdgcn_mfma_f32_16x16x32_bf16(a2[1], bh1, o, 0, 0, 0);
    return o;
}

// issue the 4 loads (fragment pair + residual pair) for pipeline slot j
#define LOAD_IT(j)                                                      \
    do {                                                                \
        fa[j] = *(const floatx4*)(xfr + (j) * TPI * H);                 \
        fb[j] = *(const floatx4*)(xfr + (j) * TPI * H + 4);             \
        ra[j] = *(const floatx4*)(xrs + (j) * TPI * H);                 \
        rb[j] = *(const floatx4*)(xrs + (j) * TPI * H + 16 * H);        \
    } while (0)

__global__ __launch_bounds__(256, 4) void ffn_kernel(
    const float* __restrict__ x,
    const float* __restrict__ ln_g,
    const float* __restrict__ ln_b,
    const float* __restrict__ w1,
    const float* __restrict__ b1,
    const float* __restrict__ w2,
    const float* __restrict__ b2,
    float* __restrict__ out,
    int ntok)
{
    const int tid = threadIdx.x;
    const int w = tid >> 6, l = tid & 63;
    const int li = l & 15, q = l >> 4;
    const int hb = q >> 1;           // 0: this lane's LN covers tile-A, 1: tile-B
    const int k0 = (q & 1) * 8;      // feature base this lane covers

    const int tok0 = blockIdx.x * BT + w * (TPI * NIT);
    // fragment ptr: own token = tok0 + hb*16 + li, features k0..k0+7
    const float* xfr = x + (size_t)(tok0 + hb * 16 + li) * H + k0;
    // residual ptr (tile A of iter 0): token tok0 + li, floats 4q..4q+3
    const float* xrs = x + (size_t)(tok0 + li) * H + 4 * q;

    // ---- bulk-issue ALL x loads first: 16 dwordx4 in flight per wave ----
    floatx4 fa[NIT], fb[NIT], ra[NIT], rb[NIT];
    #pragma unroll
    for (int p = 0; p < NIT; p++) LOAD_IT(p);

    // ---- per-lane weight fragments (L1/L2-resident after first blocks) ----
    short8 a1[4];
    #pragma unroll
    for (int mt = 0; mt < 4; mt++) {
        const int d = 16 * mt + li;
        uintx4 u = {0u, 0u, 0u, 0u};
        if (q < 2) {
            floatx4 wa = *(const floatx4*)(w1 + d * H + k0);
            floatx4 wb = *(const floatx4*)(w1 + d * H + k0 + 4);
            u.x = pk2(wa.x, wa.y); u.y = pk2(wa.z, wa.w);
            u.z = pk2(wb.x, wb.y); u.w = pk2(wb.z, wb.w);
        } else if (q == 2) {
            u.x = pk2(b1[d], 0.f);   // k=16 slot carries b1 (B-side supplies 1.0)
        }
        __builtin_memcpy(&a1[mt], &u, 16);
    }
    short8 a2[2];
    #pragma unroll
    for (int kt = 0; kt < 2; kt++) {
        floatx4 wa = *(const floatx4*)(w2 + li * D + kt * 32 + 4 * q);
        floatx4 wb = *(const floatx4*)(w2 + li * D + kt * 32 + 16 + 4 * q);
        uintx4 u = { pk2(wa.x, wa.y), pk2(wa.z, wa.w), pk2(wb.x, wb.y), pk2(wb.z, wb.w) };
        __builtin_memcpy(&a2[kt], &u, 16);
    }
    const floatx4 c2 = *(const floatx4*)(b2 + 4 * q);
    const floatx4 ga = *(const floatx4*)(ln_g + k0);
    const floatx4 gb = *(const floatx4*)(ln_g + k0 + 4);
    const floatx4 ea = *(const floatx4*)(ln_b + k0);
    const floatx4 eb = *(const floatx4*)(ln_b + k0 + 4);

    // pin the load block: nothing may be scheduled across this point,
    // so the 16 x-loads stay issued ahead of all compute.
    __builtin_amdgcn_sched_barrier(0);

    #pragma unroll
    for (int it = 0; it < NIT; ++it) {
        const floatx4 xa = fa[it], xb = fb[it];
        const int rA = (tok0 + it * TPI + li) * H + 4 * q;  // ntok*H < 2^31

        // ---- LN over this lane's 8 features (partner = lane^16) ----
        float ps = (xa.x + xa.y) + (xa.z + xa.w) + (xb.x + xb.y) + (xb.z + xb.w);
        float pq = 0.f;
        pq = fmaf(xa.x, xa.x, pq); pq = fmaf(xa.y, xa.y, pq);
        pq = fmaf(xa.z, xa.z, pq); pq = fmaf(xa.w, xa.w, pq);
        pq = fmaf(xb.x, xb.x, pq); pq = fmaf(xb.y, xb.y, pq);
        pq = fmaf(xb.z, xb.z, pq); pq = fmaf(xb.w, xb.w, pq);
        ps += __shfl_xor(ps, 16);
        pq += __shfl_xor(pq, 16);
        const float mean = ps * (1.0f / H);
        const float var  = fmaf(-mean, mean, pq * (1.0f / H));
        const float inv  = rsqrtf(var + 1e-5f);
        const float sa = inv, sb = -mean * inv;

        const float y0 = fmaf(fmaf(xa.x, sa, sb), ga.x, ea.x);
        const float y1 = fmaf(fmaf(xa.y, sa, sb), ga.y, ea.y);
        const float y2 = fmaf(fmaf(xa.z, sa, sb), ga.z, ea.z);
        const float y3 = fmaf(fmaf(xa.w, sa, sb), ga.w, ea.w);
        const float y4 = fmaf(fmaf(xb.x, sa, sb), gb.x, eb.x);
        const float y5 = fmaf(fmaf(xb.y, sa, sb), gb.y, eb.y);
        const float y6 = fmaf(fmaf(xb.z, sa, sb), gb.z, eb.z);
        const float y7 = fmaf(fmaf(xb.w, sa, sb), gb.w, eb.w);

        const unsigned p0 = pk2(y0, y1), p1 = pk2(y2, y3),
                       p2 = pk2(y4, y5), p3 = pk2(y6, y7);
        // hand tile-B's y (held by q>=2 lanes) to q<2 lanes, and vice versa
        const unsigned s0 = __shfl_xor(p0, 32), s1 = __shfl_xor(p1, 32),
                       s2 = __shfl_xor(p2, 32), s3 = __shfl_xor(p3, 32);

        const bool lo = (q < 2);
        const unsigned cq2 = (q == 2) ? 0x3F80u : 0u;  // bf16 1.0 at k=16 (b1 fold)
        uintx4 uA = { lo ? p0 : cq2, lo ? p1 : 0u, lo ? p2 : 0u, lo ? p3 : 0u };
        uintx4 uB = { lo ? s0 : cq2, lo ? s1 : 0u, lo ? s2 : 0u, lo ? s3 : 0u };
        short8 byA, byB;
        __builtin_memcpy(&byA, &uA, 16);
        __builtin_memcpy(&byB, &uB, 16);

        // ---- tile A: 16 tokens, residual + coalesced store ----
        floatx4 oA = tile_ffn(a1, a2, c2, byA);
        oA += ra[it];
        *(floatx4*)(out + rA) = oA;
        // ---- tile B ----
        floatx4 oB = tile_ffn(a1, a2, c2, byB);
        oB += rb[it];
        *(floatx4*)(out + rA + 16 * H) = oB;
    }
    (void)ntok;
}

extern "C" void kernel_launch(void* const* d_in, const int* in_sizes, int n_in,
                              void* d_out, int out_size, void* d_ws, size_t ws_size,
                              hipStream_t stream) {
    const float* x   = (const float*)d_in[0];
    const float* g   = (const float*)d_in[1];
    const float* be  = (const float*)d_in[2];
    const float* w1  = (const float*)d_in[3];
    const float* b1  = (const float*)d_in[4];
    const float* w2  = (const float*)d_in[5];
    const float* b2  = (const float*)d_in[6];
    float* out = (float*)d_out;
    const int ntok = in_sizes[0] / H;      // 1048576, divisible by BT=512

    const int grid = ntok / BT;
    ffn_kernel<<<grid, 256, 0, stream>>>(x, g, be, w1, b1, w2, b2, out, ntok);
}